// Round 1
// baseline (620.242 us; speedup 1.0000x reference)
//
#include <hip/hip_runtime.h>
#include <hip/hip_bf16.h>
#include <stdint.h>

#define D_MODEL 1024
#define HIDDEN  2048
#define N_EXP   8
#define T_TOK   8192
#define MAXPOS  17408   // 16384 assignments + 8*128 padding
#define ROWTILES (MAXPOS/128)

typedef __attribute__((ext_vector_type(4))) float f32x4;
typedef __attribute__((ext_vector_type(8))) short short8v;

__device__ __forceinline__ unsigned short f2bf(float f) {
    union { float f; unsigned int u; } v; v.f = f;
    unsigned int u = v.u;
    unsigned int r = (u + 0x7fffu + ((u >> 16) & 1u)) >> 16;  // RNE
    return (unsigned short)r;
}

__device__ __forceinline__ void gload_lds16(const void* g, void* l) {
    __builtin_amdgcn_global_load_lds(
        reinterpret_cast<const __attribute__((address_space(1))) unsigned int*>(
            reinterpret_cast<uintptr_t>(g)),
        reinterpret_cast<__attribute__((address_space(3))) unsigned int*>(
            (uint32_t)reinterpret_cast<uintptr_t>(l)),
        16, 0, 0);
}

// ---------------- fused RMSNorm + gate (fp32 routing) ----------------
__global__ void rms_gate_kernel(const float* __restrict__ x,
                                const float* __restrict__ nw,
                                const float* __restrict__ gw,
                                unsigned short* __restrict__ tb,   // bf16 t [T][D]
                                int* __restrict__ tok_e,           // [T][2]
                                float* __restrict__ tok_w,         // [T][2]
                                int* __restrict__ counts) {
    __shared__ float red[36];
    __shared__ float s_scale;
    const int t   = blockIdx.x;
    const int tid = threadIdx.x;
    const int wave = tid >> 6, lane = tid & 63;

    float4 xv = ((const float4*)(x + (size_t)t * D_MODEL))[tid];
    float4 wv = ((const float4*)nw)[tid];
    float4 tn = make_float4(xv.x * wv.x, xv.y * wv.y, xv.z * wv.z, xv.w * wv.w);

    float ssq = xv.x * xv.x + xv.y * xv.y + xv.z * xv.z + xv.w * xv.w;
    #pragma unroll
    for (int off = 32; off; off >>= 1) ssq += __shfl_xor(ssq, off);
    if (lane == 0) red[wave] = ssq;
    __syncthreads();
    if (tid == 0) {
        float s = red[0] + red[1] + red[2] + red[3];
        s_scale = rsqrtf(s * (1.0f / D_MODEL) + 1e-6f);
    }
    __syncthreads();
    const float scale = s_scale;

    // write bf16 normalized t
    ushort4 o;
    o.x = f2bf(tn.x * scale); o.y = f2bf(tn.y * scale);
    o.z = f2bf(tn.z * scale); o.w = f2bf(tn.w * scale);
    ((ushort4*)tb)[(size_t)t * 256 + tid] = o;

    // gate dots in fp32 (scale applied post-reduction; same for all experts)
    float d[8];
    #pragma unroll
    for (int e = 0; e < 8; e++) {
        float4 g = ((const float4*)(gw + e * D_MODEL))[tid];
        d[e] = tn.x * g.x + tn.y * g.y + tn.z * g.z + tn.w * g.w;
    }
    #pragma unroll
    for (int e = 0; e < 8; e++) {
        #pragma unroll
        for (int off = 32; off; off >>= 1) d[e] += __shfl_xor(d[e], off);
    }
    if (lane == 0) {
        #pragma unroll
        for (int e = 0; e < 8; e++) red[4 + e * 4 + wave] = d[e];
    }
    __syncthreads();
    if (tid == 0) {
        float lg[8];
        #pragma unroll
        for (int e = 0; e < 8; e++)
            lg[e] = (red[4+e*4] + red[4+e*4+1] + red[4+e*4+2] + red[4+e*4+3]) * scale;
        int i0 = 0;
        #pragma unroll
        for (int e = 1; e < 8; e++) if (lg[e] > lg[i0]) i0 = e;   // ties -> lowest idx
        int i1 = -1;
        #pragma unroll
        for (int e = 0; e < 8; e++)
            if (e != i0 && (i1 < 0 || lg[e] > lg[i1])) i1 = e;
        float e1 = expf(lg[i1] - lg[i0]);
        float w0 = 1.0f / (1.0f + e1);
        tok_e[2 * t] = i0;  tok_e[2 * t + 1] = i1;
        tok_w[2 * t] = w0;  tok_w[2 * t + 1] = e1 * w0;
        atomicAdd(&counts[i0], 1);
        atomicAdd(&counts[i1], 1);
    }
}

// ---------------- fp32 -> bf16 weight convert ----------------
__global__ void cvt_bf16_kernel(const float4* __restrict__ in,
                                ushort4* __restrict__ outp, int n4) {
    int i = blockIdx.x * blockDim.x + threadIdx.x;
    if (i >= n4) return;
    float4 v = in[i];
    ushort4 o; o.x = f2bf(v.x); o.y = f2bf(v.y); o.z = f2bf(v.z); o.w = f2bf(v.w);
    outp[i] = o;
}

// ---------------- padded-offset scan + perm fill ----------------
__global__ void scan_fill_kernel(int* __restrict__ perm_tok, float* __restrict__ perm_w,
                                 const int* __restrict__ counts,
                                 int* __restrict__ poff, int* __restrict__ pos_ctr) {
    int i = blockIdx.x * 256 + threadIdx.x;
    if (i < MAXPOS) { perm_tok[i] = 0; perm_w[i] = 0.0f; }
    if (blockIdx.x == 0 && threadIdx.x == 0) {
        int acc = 0; poff[0] = 0;
        #pragma unroll
        for (int e = 0; e < 8; e++) {
            pos_ctr[e] = 0;
            acc += (counts[e] + 127) & ~127;
            poff[e + 1] = acc;
        }
    }
}

// ---------------- scatter assignments into padded segments ----------------
__global__ void scatter_kernel(const int* __restrict__ tok_e, const float* __restrict__ tok_w,
                               const int* __restrict__ poff, int* __restrict__ pos_ctr,
                               int* __restrict__ perm_tok, float* __restrict__ perm_w) {
    int t = blockIdx.x * 256 + threadIdx.x;
    if (t >= T_TOK) return;
    #pragma unroll
    for (int k = 0; k < 2; k++) {
        int e = tok_e[2 * t + k];
        int p = poff[e] + atomicAdd(&pos_ctr[e], 1);
        perm_tok[p] = t;
        perm_w[p] = tok_w[2 * t + k];
    }
}

// ---------------- grouped GEMM (m97 structure: 128x128 tile, BK=64) ----------------
// MODE 1: C = gelu(A_gathered @ W^T + b) -> bf16 Hout     (K=1024, N=2048)
// MODE 2: out[tok] += w * (A @ W^T + b)  via atomicAdd    (K=2048, N=1024)
template <int MODE, int K, int N>
__global__ void moe_gemm_kernel(const unsigned short* __restrict__ A,
                                const unsigned short* __restrict__ W,
                                const float* __restrict__ bias,
                                const int* __restrict__ perm_tok,
                                const float* __restrict__ perm_w,
                                const int* __restrict__ poff,
                                unsigned short* __restrict__ Hout,
                                float* __restrict__ Out) {
    constexpr int NT = N / 128;
    __shared__ short lds[2 * 128 * 64];
    short* Asm = lds;
    short* Bsm = lds + 128 * 64;

    const int rt = blockIdx.x / NT, nt = blockIdx.x % NT;
    const int row_base = rt * 128;
    if (row_base >= poff[8]) return;
    int e = 0;
    while (poff[e + 1] <= row_base) ++e;
    const int n0 = nt * 128;

    const int tid = threadIdx.x;
    const int wave = tid >> 6, lane = tid & 63;
    const int colb = (tid & 7) * 16;                 // byte offset within 128B K-chunk
    const int wr = wave >> 1, wc = wave & 1;

    size_t aoff[4], boff[4];
    #pragma unroll
    for (int i = 0; i < 4; i++) {
        int r = row_base + i * 32 + (tid >> 3);
        int arow = (MODE == 1) ? perm_tok[r] : r;
        aoff[i] = (size_t)arow * (K * 2);
        int brow = n0 + i * 32 + (tid >> 3);
        boff[i] = ((size_t)e * N + brow) * (size_t)(K * 2);
    }
    const char* Ab = (const char*)A;
    const char* Wb = (const char*)W;

    f32x4 acc[4][4];
    #pragma unroll
    for (int mi = 0; mi < 4; mi++)
        #pragma unroll
        for (int ni = 0; ni < 4; ni++) acc[mi][ni] = (f32x4)(0.0f);

    for (int k0b = 0; k0b < K * 2; k0b += 128) {
        #pragma unroll
        for (int i = 0; i < 4; i++) {
            gload_lds16(Ab + aoff[i] + k0b + colb, (char*)Asm + i * 4096 + wave * 1024);
            gload_lds16(Wb + boff[i] + k0b + colb, (char*)Bsm + i * 4096 + wave * 1024);
        }
        __syncthreads();   // drains vmcnt before barrier (compiler-inserted)
        #pragma unroll
        for (int kk = 0; kk < 2; kk++) {
            short8v af[4], bf[4];
            #pragma unroll
            for (int mi = 0; mi < 4; mi++)
                af[mi] = *(const short8v*)&Asm[(wr * 64 + mi * 16 + (lane & 15)) * 64 + kk * 32 + (lane >> 4) * 8];
            #pragma unroll
            for (int ni = 0; ni < 4; ni++)
                bf[ni] = *(const short8v*)&Bsm[(wc * 64 + ni * 16 + (lane & 15)) * 64 + kk * 32 + (lane >> 4) * 8];
            #pragma unroll
            for (int mi = 0; mi < 4; mi++)
                #pragma unroll
                for (int ni = 0; ni < 4; ni++)
                    acc[mi][ni] = __builtin_amdgcn_mfma_f32_16x16x32_bf16(af[mi], bf[ni], acc[mi][ni], 0, 0, 0);
        }
        __syncthreads();
    }

    if (MODE == 1) {
        #pragma unroll
        for (int mi = 0; mi < 4; mi++) {
            #pragma unroll
            for (int ni = 0; ni < 4; ni++) {
                int c = n0 + wc * 64 + ni * 16 + (lane & 15);
                float bv = bias[e * N + c];
                #pragma unroll
                for (int j = 0; j < 4; j++) {
                    int r = row_base + wr * 64 + mi * 16 + (lane >> 4) * 4 + j;
                    float v = acc[mi][ni][j] + bv;
                    v = 0.5f * v * (1.0f + erff(v * 0.70710678118654752f));  // exact gelu
                    Hout[(size_t)r * N + c] = f2bf(v);
                }
            }
        }
    } else {
        #pragma unroll
        for (int mi = 0; mi < 4; mi++) {
            #pragma unroll
            for (int j = 0; j < 4; j++) {
                int r = row_base + wr * 64 + mi * 16 + (lane >> 4) * 4 + j;
                float wgt = perm_w[r];
                if (wgt != 0.0f) {
                    int tok = perm_tok[r];
                    float* orow = Out + (size_t)tok * N;
                    #pragma unroll
                    for (int ni = 0; ni < 4; ni++) {
                        int c = n0 + wc * 64 + ni * 16 + (lane & 15);
                        atomicAdd(&orow[c], wgt * (acc[mi][ni][j] + bias[e * N + c]));
                    }
                }
            }
        }
    }
}

// ---------------- launch ----------------
extern "C" void kernel_launch(void* const* d_in, const int* in_sizes, int n_in,
                              void* d_out, int out_size, void* d_ws, size_t ws_size,
                              hipStream_t stream) {
    const float* x  = (const float*)d_in[0];
    const float* nw = (const float*)d_in[1];
    const float* gw = (const float*)d_in[2];
    const float* w1 = (const float*)d_in[3];
    const float* b1 = (const float*)d_in[4];
    const float* w2 = (const float*)d_in[5];
    const float* b2 = (const float*)d_in[6];
    float* out = (float*)d_out;
    char* ws = (char*)d_ws;

    size_t off = 0;
    unsigned short* tb  = (unsigned short*)(ws + off); off += (size_t)T_TOK * D_MODEL * 2;       // 16 MiB
    unsigned short* w1b = (unsigned short*)(ws + off); off += (size_t)N_EXP * HIDDEN * D_MODEL * 2; // 32 MiB
    unsigned short* w2b = (unsigned short*)(ws + off); off += (size_t)N_EXP * D_MODEL * HIDDEN * 2; // 32 MiB
    unsigned short* h   = (unsigned short*)(ws + off); off += (size_t)MAXPOS * HIDDEN * 2;       // 68 MiB
    int*   perm_tok = (int*)(ws + off);   off += MAXPOS * 4;
    float* perm_w   = (float*)(ws + off); off += MAXPOS * 4;
    int*   tok_e    = (int*)(ws + off);   off += T_TOK * 2 * 4;
    float* tok_w    = (float*)(ws + off); off += T_TOK * 2 * 4;
    int*   meta     = (int*)(ws + off);   // counts[8] | pos_ctr[8] | poff[9]
    int* counts  = meta;
    int* pos_ctr = meta + 8;
    int* poff    = meta + 16;

    hipMemsetAsync(meta, 0, 32, stream);                                   // zero counts
    hipMemcpyAsync(out, x, (size_t)T_TOK * D_MODEL * 4,
                   hipMemcpyDeviceToDevice, stream);                        // out = x

    rms_gate_kernel<<<T_TOK, 256, 0, stream>>>(x, nw, gw, tb, tok_e, tok_w, counts);

    const int n4 = N_EXP * HIDDEN * D_MODEL / 4;   // 4,194,304 float4 per weight tensor
    cvt_bf16_kernel<<<n4 / 256, 256, 0, stream>>>((const float4*)w1, (ushort4*)w1b, n4);
    cvt_bf16_kernel<<<n4 / 256, 256, 0, stream>>>((const float4*)w2, (ushort4*)w2b, n4);

    scan_fill_kernel<<<MAXPOS / 256, 256, 0, stream>>>(perm_tok, perm_w, counts, poff, pos_ctr);
    scatter_kernel<<<T_TOK / 256, 256, 0, stream>>>(tok_e, tok_w, poff, pos_ctr, perm_tok, perm_w);

    moe_gemm_kernel<1, D_MODEL, HIDDEN><<<ROWTILES * (HIDDEN / 128), 256, 0, stream>>>(
        tb, w1b, b1, perm_tok, perm_w, poff, h, nullptr);
    moe_gemm_kernel<2, HIDDEN, D_MODEL><<<ROWTILES * (D_MODEL / 128), 256, 0, stream>>>(
        h, w2b, b2, perm_tok, perm_w, poff, nullptr, out);
}

// Round 2
// 356.924 us; speedup vs baseline: 1.7377x; 1.7377x over previous
//
#include <hip/hip_runtime.h>
#include <hip/hip_bf16.h>
#include <stdint.h>

#define D_MODEL 1024
#define HIDDEN  2048
#define N_EXP   8
#define T_TOK   8192
#define MAXPOS  17408   // 16384 assignments + 8*128 padding
#define ROWTILES (MAXPOS/128)

typedef __attribute__((ext_vector_type(4))) float f32x4;
typedef __attribute__((ext_vector_type(8))) short short8v;

__device__ __forceinline__ unsigned short f2bf(float f) {
    union { float f; unsigned int u; } v; v.f = f;
    unsigned int u = v.u;
    unsigned int r = (u + 0x7fffu + ((u >> 16) & 1u)) >> 16;  // RNE
    return (unsigned short)r;
}

__device__ __forceinline__ void gload_lds16(const void* g, void* l) {
    __builtin_amdgcn_global_load_lds(
        reinterpret_cast<const __attribute__((address_space(1))) unsigned int*>(
            reinterpret_cast<uintptr_t>(g)),
        reinterpret_cast<__attribute__((address_space(3))) unsigned int*>(
            (uint32_t)reinterpret_cast<uintptr_t>(l)),
        16, 0, 0);
}

// ---------------- fused RMSNorm + gate: one WAVE per token, no atomics ----------------
__global__ void rms_gate_kernel(const float* __restrict__ x,
                                const float* __restrict__ nw,
                                const float* __restrict__ gw,
                                unsigned short* __restrict__ tb,   // bf16 t [T][D]
                                int* __restrict__ tok_e,           // [T][2]
                                float* __restrict__ tok_w) {       // [T][2]
    const int wave = threadIdx.x >> 6;
    const int lane = threadIdx.x & 63;
    const int t = blockIdx.x * 4 + wave;

    const float4* xr = (const float4*)(x + (size_t)t * D_MODEL);
    const float4* wr = (const float4*)nw;
    float4 xv[4], wv[4];
    #pragma unroll
    for (int j = 0; j < 4; j++) {
        xv[j] = xr[j * 64 + lane];
        wv[j] = wr[j * 64 + lane];
    }

    float ssq = 0.0f;
    #pragma unroll
    for (int j = 0; j < 4; j++)
        ssq += xv[j].x * xv[j].x + xv[j].y * xv[j].y + xv[j].z * xv[j].z + xv[j].w * xv[j].w;
    #pragma unroll
    for (int off = 32; off; off >>= 1) ssq += __shfl_xor(ssq, off);
    const float scale = rsqrtf(ssq * (1.0f / D_MODEL) + 1e-6f);

    float4 tn[4];
    #pragma unroll
    for (int j = 0; j < 4; j++) {
        tn[j].x = xv[j].x * wv[j].x * scale;
        tn[j].y = xv[j].y * wv[j].y * scale;
        tn[j].z = xv[j].z * wv[j].z * scale;
        tn[j].w = xv[j].w * wv[j].w * scale;
    }

    ushort4* tw = (ushort4*)(tb + (size_t)t * D_MODEL);
    #pragma unroll
    for (int j = 0; j < 4; j++) {
        ushort4 o;
        o.x = f2bf(tn[j].x); o.y = f2bf(tn[j].y);
        o.z = f2bf(tn[j].z); o.w = f2bf(tn[j].w);
        tw[j * 64 + lane] = o;
    }

    // gate dots (fp32)
    float d[8];
    #pragma unroll
    for (int e = 0; e < 8; e++) {
        d[e] = 0.0f;
        #pragma unroll
        for (int j = 0; j < 4; j++) {
            float4 g = ((const float4*)(gw + e * D_MODEL))[j * 64 + lane];
            d[e] += tn[j].x * g.x + tn[j].y * g.y + tn[j].z * g.z + tn[j].w * g.w;
        }
    }
    #pragma unroll
    for (int e = 0; e < 8; e++) {
        #pragma unroll
        for (int off = 32; off; off >>= 1) d[e] += __shfl_xor(d[e], off);
    }

    if (lane == 0) {
        int i0 = 0;
        #pragma unroll
        for (int e = 1; e < 8; e++) if (d[e] > d[i0]) i0 = e;   // ties -> lowest idx
        int i1 = -1;
        #pragma unroll
        for (int e = 0; e < 8; e++)
            if (e != i0 && (i1 < 0 || d[e] > d[i1])) i1 = e;
        float e1 = expf(d[i1] - d[i0]);
        float w0 = 1.0f / (1.0f + e1);
        ((int2*)tok_e)[t]   = make_int2(i0, i1);
        ((float2*)tok_w)[t] = make_float2(w0, e1 * w0);
    }
}

// ---------------- histogram: LDS-local, 8 global atomics per block ----------------
__global__ void hist_kernel(const int* __restrict__ tok_e, int* __restrict__ counts) {
    __shared__ int lh[8];
    if (threadIdx.x < 8) lh[threadIdx.x] = 0;
    __syncthreads();
    int i = blockIdx.x * 512 + threadIdx.x;      // 32 blocks x 256 thr, 2 entries each
    atomicAdd(&lh[tok_e[i]], 1);
    atomicAdd(&lh[tok_e[i + 256]], 1);
    __syncthreads();
    if (threadIdx.x < 8) atomicAdd(&counts[threadIdx.x], lh[threadIdx.x]);
}

// ---------------- padded-offset scan + perm zero-fill ----------------
__global__ void scan_fill_kernel(int* __restrict__ perm_tok, float* __restrict__ perm_w,
                                 const int* __restrict__ counts,
                                 int* __restrict__ poff, int* __restrict__ pos_ctr) {
    int i = blockIdx.x * 256 + threadIdx.x;
    if (i < MAXPOS) { perm_tok[i] = 0; perm_w[i] = 0.0f; }
    if (blockIdx.x == 0 && threadIdx.x == 0) {
        int acc = 0; poff[0] = 0;
        #pragma unroll
        for (int e = 0; e < 8; e++) {
            pos_ctr[e] = 0;
            acc += (counts[e] + 127) & ~127;
            poff[e + 1] = acc;
        }
    }
}

// ---------------- scatter: block-level LDS reservation, 8 global atomics/block ----------------
__global__ void scatter_kernel(const int* __restrict__ tok_e, const float* __restrict__ tok_w,
                               const int* __restrict__ poff, int* __restrict__ pos_ctr,
                               int* __restrict__ perm_tok, float* __restrict__ perm_w) {
    __shared__ int lh[8], lbase[8];
    if (threadIdx.x < 8) lh[threadIdx.x] = 0;
    __syncthreads();
    int t = blockIdx.x * 256 + threadIdx.x;      // 32 blocks x 256 tokens
    int2   ee = ((const int2*)tok_e)[t];
    float2 ww = ((const float2*)tok_w)[t];
    int p0 = atomicAdd(&lh[ee.x], 1);
    int p1 = atomicAdd(&lh[ee.y], 1);
    __syncthreads();
    if (threadIdx.x < 8) lbase[threadIdx.x] = atomicAdd(&pos_ctr[threadIdx.x], lh[threadIdx.x]);
    __syncthreads();
    int q0 = poff[ee.x] + lbase[ee.x] + p0;
    int q1 = poff[ee.y] + lbase[ee.y] + p1;
    perm_tok[q0] = t; perm_w[q0] = ww.x;
    perm_tok[q1] = t; perm_w[q1] = ww.y;
}

// ---------------- fp32 -> bf16 weight convert ----------------
__global__ void cvt_bf16_kernel(const float4* __restrict__ in,
                                ushort4* __restrict__ outp, int n4) {
    int i = blockIdx.x * blockDim.x + threadIdx.x;
    if (i >= n4) return;
    float4 v = in[i];
    ushort4 o; o.x = f2bf(v.x); o.y = f2bf(v.y); o.z = f2bf(v.z); o.w = f2bf(v.w);
    outp[i] = o;
}

// ---------------- grouped GEMM (m97 structure: 128x128 tile, BK=64) ----------------
// MODE 1: C = gelu(A_gathered @ W^T + b) -> bf16 Hout     (K=1024, N=2048)
// MODE 2: out[tok] += w * (A @ W^T + b)  via atomicAdd    (K=2048, N=1024)
template <int MODE, int K, int N>
__global__ void moe_gemm_kernel(const unsigned short* __restrict__ A,
                                const unsigned short* __restrict__ W,
                                const float* __restrict__ bias,
                                const int* __restrict__ perm_tok,
                                const float* __restrict__ perm_w,
                                const int* __restrict__ poff,
                                unsigned short* __restrict__ Hout,
                                float* __restrict__ Out) {
    constexpr int NT = N / 128;
    __shared__ short lds[2 * 128 * 64];
    short* Asm = lds;
    short* Bsm = lds + 128 * 64;

    // T1: XCD-aware swizzle (grid % 8 == 0 for both instantiations)
    const int nwg = gridDim.x;
    const int cpx = nwg >> 3;
    const int bid = (int)blockIdx.x;
    const int swz = (bid & 7) * cpx + (bid >> 3);

    const int rt = swz / NT, nt = swz % NT;
    const int row_base = rt * 128;
    if (row_base >= poff[8]) return;
    int e = 0;
    while (poff[e + 1] <= row_base) ++e;
    const int n0 = nt * 128;

    const int tid = threadIdx.x;
    const int wave = tid >> 6, lane = tid & 63;
    const int colb = (tid & 7) * 16;                 // byte offset within 128B K-chunk
    const int wr = wave >> 1, wc = wave & 1;

    size_t aoff[4], boff[4];
    #pragma unroll
    for (int i = 0; i < 4; i++) {
        int r = row_base + i * 32 + (tid >> 3);
        int arow = (MODE == 1) ? perm_tok[r] : r;
        aoff[i] = (size_t)arow * (K * 2);
        int brow = n0 + i * 32 + (tid >> 3);
        boff[i] = ((size_t)e * N + brow) * (size_t)(K * 2);
    }
    const char* Ab = (const char*)A;
    const char* Wb = (const char*)W;

    f32x4 acc[4][4];
    #pragma unroll
    for (int mi = 0; mi < 4; mi++)
        #pragma unroll
        for (int ni = 0; ni < 4; ni++) acc[mi][ni] = (f32x4)(0.0f);

    for (int k0b = 0; k0b < K * 2; k0b += 128) {
        #pragma unroll
        for (int i = 0; i < 4; i++) {
            gload_lds16(Ab + aoff[i] + k0b + colb, (char*)Asm + i * 4096 + wave * 1024);
            gload_lds16(Wb + boff[i] + k0b + colb, (char*)Bsm + i * 4096 + wave * 1024);
        }
        __syncthreads();
        #pragma unroll
        for (int kk = 0; kk < 2; kk++) {
            short8v af[4], bf[4];
            #pragma unroll
            for (int mi = 0; mi < 4; mi++)
                af[mi] = *(const short8v*)&Asm[(wr * 64 + mi * 16 + (lane & 15)) * 64 + kk * 32 + (lane >> 4) * 8];
            #pragma unroll
            for (int ni = 0; ni < 4; ni++)
                bf[ni] = *(const short8v*)&Bsm[(wc * 64 + ni * 16 + (lane & 15)) * 64 + kk * 32 + (lane >> 4) * 8];
            #pragma unroll
            for (int mi = 0; mi < 4; mi++)
                #pragma unroll
                for (int ni = 0; ni < 4; ni++)
                    acc[mi][ni] = __builtin_amdgcn_mfma_f32_16x16x32_bf16(af[mi], bf[ni], acc[mi][ni], 0, 0, 0);
        }
        __syncthreads();
    }

    if (MODE == 1) {
        #pragma unroll
        for (int mi = 0; mi < 4; mi++) {
            #pragma unroll
            for (int ni = 0; ni < 4; ni++) {
                int c = n0 + wc * 64 + ni * 16 + (lane & 15);
                float bv = bias[e * N + c];
                #pragma unroll
                for (int j = 0; j < 4; j++) {
                    int r = row_base + wr * 64 + mi * 16 + (lane >> 4) * 4 + j;
                    float v = acc[mi][ni][j] + bv;
                    v = 0.5f * v * (1.0f + erff(v * 0.70710678118654752f));  // exact gelu
                    Hout[(size_t)r * N + c] = f2bf(v);
                }
            }
        }
    } else {
        #pragma unroll
        for (int mi = 0; mi < 4; mi++) {
            #pragma unroll
            for (int j = 0; j < 4; j++) {
                int r = row_base + wr * 64 + mi * 16 + (lane >> 4) * 4 + j;
                float wgt = perm_w[r];
                if (wgt != 0.0f) {
                    int tok = perm_tok[r];
                    float* orow = Out + (size_t)tok * N;
                    #pragma unroll
                    for (int ni = 0; ni < 4; ni++) {
                        int c = n0 + wc * 64 + ni * 16 + (lane & 15);
                        atomicAdd(&orow[c], wgt * (acc[mi][ni][j] + bias[e * N + c]));
                    }
                }
            }
        }
    }
}

// ---------------- launch ----------------
extern "C" void kernel_launch(void* const* d_in, const int* in_sizes, int n_in,
                              void* d_out, int out_size, void* d_ws, size_t ws_size,
                              hipStream_t stream) {
    const float* x  = (const float*)d_in[0];
    const float* nw = (const float*)d_in[1];
    const float* gw = (const float*)d_in[2];
    const float* w1 = (const float*)d_in[3];
    const float* b1 = (const float*)d_in[4];
    const float* w2 = (const float*)d_in[5];
    const float* b2 = (const float*)d_in[6];
    float* out = (float*)d_out;
    char* ws = (char*)d_ws;

    size_t off = 0;
    unsigned short* tb  = (unsigned short*)(ws + off); off += (size_t)T_TOK * D_MODEL * 2;
    unsigned short* w1b = (unsigned short*)(ws + off); off += (size_t)N_EXP * HIDDEN * D_MODEL * 2;
    unsigned short* w2b = (unsigned short*)(ws + off); off += (size_t)N_EXP * D_MODEL * HIDDEN * 2;
    unsigned short* h   = (unsigned short*)(ws + off); off += (size_t)MAXPOS * HIDDEN * 2;
    int*   perm_tok = (int*)(ws + off);   off += MAXPOS * 4;
    float* perm_w   = (float*)(ws + off); off += MAXPOS * 4;
    int*   tok_e    = (int*)(ws + off);   off += T_TOK * 2 * 4;
    float* tok_w    = (float*)(ws + off); off += T_TOK * 2 * 4;
    int*   meta     = (int*)(ws + off);   // counts[8] | pos_ctr[8] | poff[9]
    int* counts  = meta;
    int* pos_ctr = meta + 8;
    int* poff    = meta + 16;

    hipMemsetAsync(meta, 0, 32, stream);                                   // zero counts
    hipMemcpyAsync(out, x, (size_t)T_TOK * D_MODEL * 4,
                   hipMemcpyDeviceToDevice, stream);                        // out = x

    rms_gate_kernel<<<T_TOK / 4, 256, 0, stream>>>(x, nw, gw, tb, tok_e, tok_w);

    const int n4 = N_EXP * HIDDEN * D_MODEL / 4;
    cvt_bf16_kernel<<<n4 / 256, 256, 0, stream>>>((const float4*)w1, (ushort4*)w1b, n4);
    cvt_bf16_kernel<<<n4 / 256, 256, 0, stream>>>((const float4*)w2, (ushort4*)w2b, n4);

    hist_kernel<<<32, 256, 0, stream>>>(tok_e, counts);
    scan_fill_kernel<<<MAXPOS / 256, 256, 0, stream>>>(perm_tok, perm_w, counts, poff, pos_ctr);
    scatter_kernel<<<T_TOK / 256, 256, 0, stream>>>(tok_e, tok_w, poff, pos_ctr, perm_tok, perm_w);

    moe_gemm_kernel<1, D_MODEL, HIDDEN><<<ROWTILES * (HIDDEN / 128), 256, 0, stream>>>(
        tb, w1b, b1, perm_tok, perm_w, poff, h, nullptr);
    moe_gemm_kernel<2, HIDDEN, D_MODEL><<<ROWTILES * (D_MODEL / 128), 256, 0, stream>>>(
        h, w2b, b2, perm_tok, perm_w, poff, nullptr, out);
}